// Round 2
// baseline (161.286 us; speedup 1.0000x reference)
//
#include <hip/hip_runtime.h>
#include <math.h>

#define NN 1536
#define DIN 256
#define DOUT 64
#define NWAY 16
#define NSUP 768
#define ROWS 3          // rows per fused block; 1536/3 = 512 blocks = 2/CU exactly

// d_out layout (floats): scores[768*16], h_out[1536*64], a[1536*1536]
#define OFF_SCORES 0
#define OFF_H 12288
#define OFF_A 110592

// d_ws layout (floats)
#define WG 0          // g[1536*64]
#define WQ 98304      // q[1536] (pre-scaled by 0.6)
#define WCODE 99840   // code[1536] int: known ? label : -1
#define WCENT 101376  // centroids[16*64]

// ---------------- g = hidden @ W^T, q_i = 0.6*<w, g_i>, mask code ----------------
__global__ __launch_bounds__(256) void k_g(const float* __restrict__ hid,
                                           const float* __restrict__ W,
                                           const float* __restrict__ attw,
                                           const int* __restrict__ labels,
                                           const int* __restrict__ zda,
                                           float* __restrict__ g,
                                           float* __restrict__ q,
                                           int* __restrict__ code) {
  int t = threadIdx.x;
  int r = t >> 6, d = t & 63;
  int i = blockIdx.x * 4 + r;
  const float4* hp = (const float4*)(hid + (size_t)i * DIN);
  const float4* wp = (const float4*)(W + (size_t)d * DIN);
  float4 acc = {0.f, 0.f, 0.f, 0.f};
#pragma unroll
  for (int k = 0; k < DIN / 4; k++) {
    float4 h4 = hp[k];
    float4 w4 = wp[k];
    acc.x = fmaf(h4.x, w4.x, acc.x);
    acc.y = fmaf(h4.y, w4.y, acc.y);
    acc.z = fmaf(h4.z, w4.z, acc.z);
    acc.w = fmaf(h4.w, w4.w, acc.w);
  }
  float gv = (acc.x + acc.y) + (acc.z + acc.w);
  g[(size_t)i * DOUT + d] = gv;
  float val = gv * attw[d];
#pragma unroll
  for (int off = 32; off >= 1; off >>= 1) val += __shfl_xor(val, off, 64);
  if (d == 0) q[i] = 0.6f * val;
  if (t < 4) {
    int ii = blockIdx.x * 4 + t;
    code[ii] = zda[ii] ? -1 : labels[ii];
  }
}

// ---------------- fused: e -> softmax -> a-write -> h = a@g ----------------
// Block owns ROWS=3 rows. 256 threads.
__global__ __launch_bounds__(256, 2) void k_fused(const float* __restrict__ g,
                                                  const float* __restrict__ q,
                                                  const int* __restrict__ code,
                                                  const float* __restrict__ attw,
                                                  float* __restrict__ aout,
                                                  float* __restrict__ hout) {
  __shared__ float e_lds[ROWS][NN];        // 18 KB; later holds normalized a
  __shared__ float gi[ROWS * DOUT];        // 768 B
  __shared__ float wl[DOUT];               // 256 B
  __shared__ float qi_s[ROWS];
  __shared__ int ci_s[ROWS];
  __shared__ float redm[ROWS][4];
  __shared__ float reds[ROWS][4];
  __shared__ float part[16 * ROWS * 68];   // ~13 KB: [jg][r][d(+pad)]

  int t = threadIdx.x;
  int r0 = blockIdx.x * ROWS;

  // stage g rows for this block's i's, attn_w, q_i, code_i
  if (t < ROWS * DOUT / 4) {
    ((float4*)gi)[t] = ((const float4*)(g + (size_t)r0 * DOUT))[t];
  }
  if (t >= 64 && t < 80) {
    ((float4*)wl)[t - 64] = ((const float4*)attw)[t - 64];
  }
  if (t >= 128 && t < 128 + ROWS) {
    qi_s[t - 128] = q[r0 + (t - 128)];
    ci_s[t - 128] = code[r0 + (t - 128)];
  }
  __syncthreads();

  // ---- phase E: e[r][j] for all j, this thread handles j = jc*256 + t ----
  for (int jc = 0; jc < NN / 256; jc++) {
    int j = jc * 256 + t;
    float4 gj[16];
    const float4* gp = (const float4*)(g + (size_t)j * DOUT);
#pragma unroll
    for (int k = 0; k < 16; k++) gj[k] = gp[k];
    float qj = q[j];
    int cj = code[j];
#pragma unroll
    for (int r = 0; r < ROWS; r++) {
      const float4* gv = (const float4*)(gi + r * DOUT);
      float4 acc = {0.f, 0.f, 0.f, 0.f};
#pragma unroll
      for (int k = 0; k < 16; k++) {
        float4 a4 = gv[k];
        float4 w4 = ((const float4*)wl)[k];
        float4 b4 = gj[k];
        acc.x = fmaf(w4.x, fabsf(a4.x + b4.x), acc.x);
        acc.y = fmaf(w4.y, fabsf(a4.y + b4.y), acc.y);
        acc.z = fmaf(w4.z, fabsf(a4.z + b4.z), acc.z);
        acc.w = fmaf(w4.w, fabsf(a4.w + b4.w), acc.w);
      }
      float e = (qi_s[r] + qj) + 0.4f * ((acc.x + acc.y) + (acc.z + acc.w));
      int cr = ci_s[r];
      if ((cr >= 0) && (cj >= 0) && (cr != cj)) e = -1e30f;
      e_lds[r][j] = e;
    }
  }

  // ---- phase SM: row softmax (each thread's 6 values per row are its own) ----
  float v[ROWS][6];
  int w = t >> 6;
#pragma unroll
  for (int r = 0; r < ROWS; r++) {
#pragma unroll
    for (int k = 0; k < 6; k++) v[r][k] = e_lds[r][t + 256 * k];
    float mm = v[r][0];
#pragma unroll
    for (int k = 1; k < 6; k++) mm = fmaxf(mm, v[r][k]);
#pragma unroll
    for (int off = 32; off >= 1; off >>= 1) mm = fmaxf(mm, __shfl_xor(mm, off, 64));
    if ((t & 63) == 0) redm[r][w] = mm;
  }
  __syncthreads();
  float inv[ROWS];
#pragma unroll
  for (int r = 0; r < ROWS; r++) {
    float m = fmaxf(fmaxf(redm[r][0], redm[r][1]), fmaxf(redm[r][2], redm[r][3]));
    float ss = 0.f;
#pragma unroll
    for (int k = 0; k < 6; k++) {
      v[r][k] = __expf(v[r][k] - m);
      ss += v[r][k];
    }
#pragma unroll
    for (int off = 32; off >= 1; off >>= 1) ss += __shfl_xor(ss, off, 64);
    if ((t & 63) == 0) reds[r][w] = ss;
  }
  __syncthreads();
#pragma unroll
  for (int r = 0; r < ROWS; r++) {
    float s = (reds[r][0] + reds[r][1]) + (reds[r][2] + reds[r][3]);
    inv[r] = 1.f / s;
  }
#pragma unroll
  for (int r = 0; r < ROWS; r++) {
#pragma unroll
    for (int k = 0; k < 6; k++) {
      int j = t + 256 * k;
      float av = v[r][k] * inv[r];
      e_lds[r][j] = av;
      aout[(size_t)(r0 + r) * NN + j] = av;
    }
  }
  __syncthreads();

  // ---- phase H: h[r0+r][:] = sum_j a[r][j] * g[j][:], 16-way j split ----
  int jg = t >> 4, d4 = t & 15;
  float4 hacc[ROWS];
#pragma unroll
  for (int r = 0; r < ROWS; r++) hacc[r] = make_float4(0.f, 0.f, 0.f, 0.f);
#pragma unroll 4
  for (int jj = 0; jj < NN / 16; jj++) {
    int j = jj * 16 + jg;
    float4 g4 = *(const float4*)(g + (size_t)j * DOUT + d4 * 4);
#pragma unroll
    for (int r = 0; r < ROWS; r++) {
      float av = e_lds[r][j];
      hacc[r].x = fmaf(av, g4.x, hacc[r].x);
      hacc[r].y = fmaf(av, g4.y, hacc[r].y);
      hacc[r].z = fmaf(av, g4.z, hacc[r].z);
      hacc[r].w = fmaf(av, g4.w, hacc[r].w);
    }
  }
#pragma unroll
  for (int r = 0; r < ROWS; r++) {
    *(float4*)(part + (jg * ROWS + r) * 68 + d4 * 4) = hacc[r];
  }
  __syncthreads();
  if (t < ROWS * DOUT) {
    int r = t >> 6, d = t & 63;
    float s = 0.f;
#pragma unroll
    for (int k = 0; k < 16; k++) s += part[(k * ROWS + r) * 68 + d];
    hout[(size_t)(r0 + r) * DOUT + d] = s;
  }
}

// ---------------- centroids (one block per class) ----------------
__global__ __launch_bounds__(256) void k_cent(const float* __restrict__ h,
                                              const int* __restrict__ labels,
                                              float* __restrict__ cent) {
  __shared__ float part[4][64];
  __shared__ int pc[4];
  int c = blockIdx.x, t = threadIdx.x;
  int d = t & 63, rq = t >> 6;
  float acc = 0.f;
  int cnt = 0;
  for (int r = rq; r < NSUP; r += 4) {
    int lab = labels[r];
    if (lab == c) { acc += h[(size_t)r * DOUT + d]; cnt++; }
  }
  part[rq][d] = acc;
  if (d == 0) pc[rq] = cnt;
  __syncthreads();
  if (t < 64) {
    float num = part[0][t] + part[1][t] + part[2][t] + part[3][t];
    int count = pc[0] + pc[1] + pc[2] + pc[3];
    cent[c * DOUT + t] = (count > 0) ? (num / (float)count) : 0.f;
  }
}

// ---------------- scores = 1/(dist(query, centroid)+1e-10) ----------------
__global__ __launch_bounds__(256) void k_scores(const float* __restrict__ h,
                                                const float* __restrict__ cent,
                                                float* __restrict__ scores) {
  __shared__ float cl[NWAY * 65];
  __shared__ float hl[16 * 65];
  int t = threadIdx.x;
  int q0 = blockIdx.x * 16;
#pragma unroll
  for (int u = 0; u < 4; u++) {
    int f = t + u * 256;
    int row = f >> 6, k = f & 63;
    cl[row * 65 + k] = cent[f];
    hl[row * 65 + k] = h[(size_t)(NSUP + q0) * DOUT + f];
  }
  __syncthreads();
  int qr = t >> 4, c = t & 15;
  const float* hv = hl + qr * 65;
  const float* cv = cl + c * 65;
  float hh = 0.f, cc = 0.f, hc = 0.f;
#pragma unroll
  for (int k = 0; k < DOUT; k++) {
    float av = hv[k], bv = cv[k];
    hh = fmaf(av, av, hh);
    cc = fmaf(bv, bv, cc);
    hc = fmaf(av, bv, hc);
  }
  float d2 = fmaxf(hh + cc - 2.f * hc, 0.f);
  scores[q0 * NWAY + t] = 1.f / (sqrtf(d2) + 1e-10f);
}

extern "C" void kernel_launch(void* const* d_in, const int* in_sizes, int n_in,
                              void* d_out, int out_size, void* d_ws, size_t ws_size,
                              hipStream_t stream) {
  const float* hid = (const float*)d_in[0];
  const float* W = (const float*)d_in[1];
  const float* attw = (const float*)d_in[2];
  const int* labels = (const int*)d_in[3];
  const int* zda = (const int*)d_in[4];
  float* out = (float*)d_out;
  float* ws = (float*)d_ws;

  float* g = ws + WG;
  float* q = ws + WQ;
  int* code = (int*)(ws + WCODE);
  float* cent = ws + WCENT;
  float* scores = out + OFF_SCORES;
  float* h = out + OFF_H;
  float* a = out + OFF_A;

  hipLaunchKernelGGL(k_g, dim3(NN / 4), dim3(256), 0, stream, hid, W, attw, labels, zda, g, q, code);
  hipLaunchKernelGGL(k_fused, dim3(NN / ROWS), dim3(256), 0, stream, g, q, code, attw, a, h);
  hipLaunchKernelGGL(k_cent, dim3(NWAY), dim3(256), 0, stream, h, labels, cent);
  hipLaunchKernelGGL(k_scores, dim3(NSUP / 16), dim3(256), 0, stream, h, cent, scores);
}

// Round 3
// 107.332 us; speedup vs baseline: 1.5027x; 1.5027x over previous
//
#include <hip/hip_runtime.h>
#include <math.h>

#define NN 1536
#define DIN 256
#define DOUT 64
#define NWAY 16
#define NSUP 768

// d_out layout (floats): scores[768*16], h_out[1536*64], a[1536*1536]
#define OFF_SCORES 0
#define OFF_H 12288
#define OFF_A 110592

// d_ws layout (floats)
#define WG 0          // g[1536*64]
#define WQ 98304      // q[1536] (pre-scaled by 0.6)
#define WCODE 99840   // code[1536] int: known ? label : -1
#define WCENT 101376  // centroids[16*64]
#define WHP 102400    // h partials [12][1536][64]

// ---------------- g = hidden @ W^T, q_i = 0.6*<w, g_i>, mask code ----------------
__global__ __launch_bounds__(256) void k_g(const float* __restrict__ hid,
                                           const float* __restrict__ W,
                                           const float* __restrict__ attw,
                                           const int* __restrict__ labels,
                                           const int* __restrict__ zda,
                                           float* __restrict__ g,
                                           float* __restrict__ q,
                                           int* __restrict__ code) {
  int t = threadIdx.x;
  int r = t >> 6, d = t & 63;
  int i = blockIdx.x * 4 + r;
  const float4* hp = (const float4*)(hid + (size_t)i * DIN);
  const float4* wp = (const float4*)(W + (size_t)d * DIN);
  float4 acc = {0.f, 0.f, 0.f, 0.f};
#pragma unroll
  for (int k = 0; k < DIN / 4; k++) {
    float4 h4 = hp[k];
    float4 w4 = wp[k];
    acc.x = fmaf(h4.x, w4.x, acc.x);
    acc.y = fmaf(h4.y, w4.y, acc.y);
    acc.z = fmaf(h4.z, w4.z, acc.z);
    acc.w = fmaf(h4.w, w4.w, acc.w);
  }
  float gv = (acc.x + acc.y) + (acc.z + acc.w);
  g[(size_t)i * DOUT + d] = gv;
  float val = gv * attw[d];
#pragma unroll
  for (int off = 32; off >= 1; off >>= 1) val += __shfl_xor(val, off, 64);
  if (d == 0) q[i] = 0.6f * val;
  if (t < 4) {
    int ii = blockIdx.x * 4 + t;
    code[ii] = zda[ii] ? -1 : labels[ii];
  }
}

// ---------------- e[i][j]: grid(192 i-tiles, 6 j-chunks), thread owns j ----------------
// i-tile fast-varying => active blocks share the same 64KB j-chunk of g in L2.
__global__ __launch_bounds__(256) void k_e(const float* __restrict__ g,
                                           const float* __restrict__ q,
                                           const int* __restrict__ code,
                                           const float* __restrict__ attw,
                                           float* __restrict__ aout) {
  __shared__ float gi[8 * DOUT];   // 2 KB
  __shared__ float wl[DOUT];       // 256 B
  __shared__ float qi[8];
  __shared__ int ci[8];
  int t = threadIdx.x;
  int i0 = blockIdx.x * 8;
  int j = blockIdx.y * 256 + t;

  if (t < 128) {
    ((float4*)gi)[t] = ((const float4*)(g + (size_t)i0 * DOUT))[t];
  } else if (t < 144) {
    ((float4*)wl)[t - 128] = ((const float4*)attw)[t - 128];
  } else if (t < 152) {
    qi[t - 144] = q[i0 + t - 144];
    ci[t - 144] = code[i0 + t - 144];
  }
  float4 gj[16];
  const float4* gp = (const float4*)(g + (size_t)j * DOUT);
#pragma unroll
  for (int k = 0; k < 16; k++) gj[k] = gp[k];
  float qj = q[j];
  int cj = code[j];
  __syncthreads();

#pragma unroll 2
  for (int u = 0; u < 8; u++) {
    const float4* gv = (const float4*)(gi + u * DOUT);
    const float4* wv = (const float4*)wl;
    float4 acc = {0.f, 0.f, 0.f, 0.f};
#pragma unroll
    for (int k = 0; k < 16; k++) {
      float4 a4 = gv[k];       // broadcast (wave-uniform) LDS read
      float4 w4 = wv[k];       // broadcast
      float4 b4 = gj[k];
      acc.x = fmaf(w4.x, fabsf(a4.x + b4.x), acc.x);
      acc.y = fmaf(w4.y, fabsf(a4.y + b4.y), acc.y);
      acc.z = fmaf(w4.z, fabsf(a4.z + b4.z), acc.z);
      acc.w = fmaf(w4.w, fabsf(a4.w + b4.w), acc.w);
    }
    float e = (qi[u] + qj) + 0.4f * ((acc.x + acc.y) + (acc.z + acc.w));
    int cu = ci[u];
    if ((cu >= 0) && (cj >= 0) && (cu != cj)) e = -1e30f;
    aout[(size_t)(i0 + u) * NN + j] = e;
  }
}

// ---------------- in-place row softmax over the a buffer ----------------
__global__ __launch_bounds__(256) void k_sm(float* __restrict__ a) {
  __shared__ float red[8];
  int i = blockIdx.x, t = threadIdx.x;
  float* row = a + (size_t)i * NN;
  float v[6];
#pragma unroll
  for (int k = 0; k < 6; k++) v[k] = row[t + 256 * k];
  float m = v[0];
#pragma unroll
  for (int k = 1; k < 6; k++) m = fmaxf(m, v[k]);
#pragma unroll
  for (int off = 32; off >= 1; off >>= 1) m = fmaxf(m, __shfl_xor(m, off, 64));
  int w = t >> 6;
  if ((t & 63) == 0) red[w] = m;
  __syncthreads();
  m = fmaxf(fmaxf(red[0], red[1]), fmaxf(red[2], red[3]));
  float s = 0.f;
#pragma unroll
  for (int k = 0; k < 6; k++) {
    v[k] = __expf(v[k] - m);
    s += v[k];
  }
#pragma unroll
  for (int off = 32; off >= 1; off >>= 1) s += __shfl_xor(s, off, 64);
  if ((t & 63) == 0) red[4 + w] = s;
  __syncthreads();
  s = (red[4] + red[5]) + (red[6] + red[7]);
  float inv = 1.f / s;
#pragma unroll
  for (int k = 0; k < 6; k++) row[t + 256 * k] = v[k] * inv;
}

// ---------------- h partial = a[:, chunk] @ g[chunk, :]  grid(96 r-tiles, 12 j-chunks) ----
__global__ __launch_bounds__(256) void k_h(const float* __restrict__ a,
                                           const float* __restrict__ g,
                                           float* __restrict__ hp) {
  __shared__ float at[16 * 132];
  __shared__ float gl[128 * 64];
  int t = threadIdx.x;
  int jc = blockIdx.y;
  int r0 = blockIdx.x * 16;
#pragma unroll
  for (int u = 0; u < 2; u++) {
    int f4 = t + u * 256;
    int row = f4 >> 5;
    int col4 = f4 & 31;
    float4 v = *(const float4*)(a + (size_t)(r0 + row) * NN + jc * 128 + col4 * 4);
    *(float4*)(at + row * 132 + col4 * 4) = v;
  }
  {
    const float4* src = (const float4*)(g + (size_t)jc * 128 * DOUT);
    float4* dst = (float4*)gl;
#pragma unroll
    for (int u = 0; u < 8; u++) dst[t + u * 256] = src[t + u * 256];
  }
  __syncthreads();
  int r = t >> 4;
  int dq = (t & 15) * 4;
  const float4* ap = (const float4*)(at + r * 132);
  float4 acc = {0.f, 0.f, 0.f, 0.f};
  for (int j4 = 0; j4 < 32; j4++) {
    float4 av = ap[j4];
    const float* gb = gl + (j4 * 4) * 64 + dq;
    float4 g0 = *(const float4*)(gb);
    float4 g1 = *(const float4*)(gb + 64);
    float4 g2 = *(const float4*)(gb + 128);
    float4 g3 = *(const float4*)(gb + 192);
    acc.x = fmaf(av.x, g0.x, acc.x); acc.y = fmaf(av.x, g0.y, acc.y);
    acc.z = fmaf(av.x, g0.z, acc.z); acc.w = fmaf(av.x, g0.w, acc.w);
    acc.x = fmaf(av.y, g1.x, acc.x); acc.y = fmaf(av.y, g1.y, acc.y);
    acc.z = fmaf(av.y, g1.z, acc.z); acc.w = fmaf(av.y, g1.w, acc.w);
    acc.x = fmaf(av.z, g2.x, acc.x); acc.y = fmaf(av.z, g2.y, acc.y);
    acc.z = fmaf(av.z, g2.z, acc.z); acc.w = fmaf(av.z, g2.w, acc.w);
    acc.x = fmaf(av.w, g3.x, acc.x); acc.y = fmaf(av.w, g3.y, acc.y);
    acc.z = fmaf(av.w, g3.z, acc.z); acc.w = fmaf(av.w, g3.w, acc.w);
  }
  *(float4*)(hp + ((size_t)jc * NN + r0 + r) * DOUT + dq) = acc;
}

// ---------------- reduce 12 partials -> h_out ----------------
__global__ __launch_bounds__(256) void k_hred(const float* __restrict__ hp,
                                              float* __restrict__ h) {
  int idx = blockIdx.x * 256 + threadIdx.x;
  float s = 0.f;
#pragma unroll
  for (int c = 0; c < 12; c++) s += hp[(size_t)c * (NN * DOUT) + idx];
  h[idx] = s;
}

// ---------------- centroids (one block per class, 1024 threads) ----------------
__global__ __launch_bounds__(1024) void k_cent(const float* __restrict__ h,
                                               const int* __restrict__ labels,
                                               float* __restrict__ cent) {
  __shared__ float part[16][64];
  __shared__ int pc[16];
  int c = blockIdx.x, t = threadIdx.x;
  int d = t & 63, rq = t >> 6;
  float acc = 0.f;
  int cnt = 0;
#pragma unroll 4
  for (int r = rq; r < NSUP; r += 16) {
    int lab = labels[r];
    if (lab == c) { acc += h[(size_t)r * DOUT + d]; cnt++; }
  }
  part[rq][d] = acc;
  if (d == 0) pc[rq] = cnt;
  __syncthreads();
  if (t < 64) {
    float num = 0.f;
    int count = 0;
#pragma unroll
    for (int k = 0; k < 16; k++) { num += part[k][t]; count += pc[k]; }
    cent[c * DOUT + t] = (count > 0) ? (num / (float)count) : 0.f;
  }
}

// ---------------- scores = 1/(dist(query, centroid)+1e-10) ----------------
__global__ __launch_bounds__(256) void k_scores(const float* __restrict__ h,
                                                const float* __restrict__ cent,
                                                float* __restrict__ scores) {
  __shared__ float cl[NWAY * 65];
  __shared__ float hl[16 * 65];
  int t = threadIdx.x;
  int q0 = blockIdx.x * 16;
#pragma unroll
  for (int u = 0; u < 4; u++) {
    int f = t + u * 256;
    int row = f >> 6, k = f & 63;
    cl[row * 65 + k] = cent[f];
    hl[row * 65 + k] = h[(size_t)(NSUP + q0) * DOUT + f];
  }
  __syncthreads();
  int qr = t >> 4, c = t & 15;
  const float* hv = hl + qr * 65;
  const float* cv = cl + c * 65;
  float hh = 0.f, cc = 0.f, hc = 0.f;
#pragma unroll
  for (int k = 0; k < DOUT; k++) {
    float av = hv[k], bv = cv[k];
    hh = fmaf(av, av, hh);
    cc = fmaf(bv, bv, cc);
    hc = fmaf(av, bv, hc);
  }
  float d2 = fmaxf(hh + cc - 2.f * hc, 0.f);
  scores[q0 * NWAY + t] = 1.f / (sqrtf(d2) + 1e-10f);
}

extern "C" void kernel_launch(void* const* d_in, const int* in_sizes, int n_in,
                              void* d_out, int out_size, void* d_ws, size_t ws_size,
                              hipStream_t stream) {
  const float* hid = (const float*)d_in[0];
  const float* W = (const float*)d_in[1];
  const float* attw = (const float*)d_in[2];
  const int* labels = (const int*)d_in[3];
  const int* zda = (const int*)d_in[4];
  float* out = (float*)d_out;
  float* ws = (float*)d_ws;

  float* g = ws + WG;
  float* q = ws + WQ;
  int* code = (int*)(ws + WCODE);
  float* cent = ws + WCENT;
  float* hp = ws + WHP;
  float* scores = out + OFF_SCORES;
  float* h = out + OFF_H;
  float* a = out + OFF_A;

  hipLaunchKernelGGL(k_g, dim3(NN / 4), dim3(256), 0, stream, hid, W, attw, labels, zda, g, q, code);
  hipLaunchKernelGGL(k_e, dim3(NN / 8, NN / 256), dim3(256), 0, stream, g, q, code, attw, a);
  hipLaunchKernelGGL(k_sm, dim3(NN), dim3(256), 0, stream, a);
  hipLaunchKernelGGL(k_h, dim3(NN / 16, NN / 128), dim3(256), 0, stream, a, g, hp);
  hipLaunchKernelGGL(k_hred, dim3(NN * DOUT / 256), dim3(256), 0, stream, hp, h);
  hipLaunchKernelGGL(k_cent, dim3(NWAY), dim3(1024), 0, stream, h, labels, cent);
  hipLaunchKernelGGL(k_scores, dim3(NSUP / 16), dim3(256), 0, stream, h, cent, scores);
}